// Round 2
// baseline (282.667 us; speedup 1.0000x reference)
//
#include <hip/hip_runtime.h>
#include <hip/hip_bf16.h>
#include <hip/hip_fp16.h>

typedef __attribute__((ext_vector_type(8))) short short8;     // bf16x8 frag
typedef __attribute__((ext_vector_type(8))) _Float16 half8;   // f16x8 frag
typedef __attribute__((ext_vector_type(4))) float f32x4;
typedef __attribute__((ext_vector_type(16))) float f32x16;
typedef __attribute__((ext_vector_type(4))) unsigned int uint4v;
typedef unsigned short u16;
typedef unsigned int u32;

#define LOG2E 1.44269504088896f

__device__ __forceinline__ u16 f2bf(float f) {
  u32 u = __builtin_bit_cast(u32, f);
  u += 0x7fffu + ((u >> 16) & 1u);
  return (u16)(u >> 16);
}
__device__ __forceinline__ u16 f2h(float f) {
  _Float16 h = (_Float16)f;
  return __builtin_bit_cast(u16, h);
}
__device__ __forceinline__ u32 cvtpk_bf16(float lo, float hi) {
  u32 r;
  asm("v_cvt_pk_bf16_f32 %0, %1, %2" : "=v"(r) : "v"(lo), "v"(hi));
  return r;
}

// ---------------------------------------------------------------------------
// K0: prep. xT[b][n][c] (f16) from x[b][c][n] (f32); W_all f16 [320][256]
// (rows 0-31 Wf, 32-63 Wg*LOG2E, 64-319 Wh); b_all f32 [320] (bg*LOG2E).
// ---------------------------------------------------------------------------
__global__ void k_prep(const float* __restrict__ x,
                       const float* __restrict__ Wf, const float* __restrict__ bfp,
                       const float* __restrict__ Wg, const float* __restrict__ bgp,
                       const float* __restrict__ Wh, const float* __restrict__ bhp,
                       u16* __restrict__ xT, u16* __restrict__ Wall,
                       float* __restrict__ ball)
{
  int bid = blockIdx.x, t = threadIdx.x;
  if (bid < 1024) {
    __shared__ u16 tile[64][68];
    int b = bid >> 8, c0 = ((bid >> 6) & 3) << 6, n0 = (bid & 63) << 6;
#pragma unroll
    for (int r = 0; r < 4; ++r) {
      int cl = (t >> 4) + r * 16, nl = (t & 15) * 4;
      const float4 v = *(const float4*)&x[(size_t)(b * 256 + c0 + cl) * 4096 + n0 + nl];
      tile[cl][nl + 0] = f2h(v.x); tile[cl][nl + 1] = f2h(v.y);
      tile[cl][nl + 2] = f2h(v.z); tile[cl][nl + 3] = f2h(v.w);
    }
    __syncthreads();
#pragma unroll
    for (int r = 0; r < 4; ++r) {
      int nl = (t >> 4) + r * 16, cl = (t & 15) * 4;
      ushort4 o;
      o.x = tile[cl + 0][nl]; o.y = tile[cl + 1][nl];
      o.z = tile[cl + 2][nl]; o.w = tile[cl + 3][nl];
      *(ushort4*)&xT[(size_t)(b * 4096 + n0 + nl) * 256 + c0 + cl] = o;
    }
  } else {
    int wb = bid - 1024;                 // 0..79
    int e = wb * 1024 + t * 4;           // element in W_all (320*256)
    int r = e >> 8;
    const float* src = (r < 32) ? (Wf + e)
                     : (r < 64) ? (Wg + e - 32 * 256)
                                : (Wh + e - 64 * 256);
    float4 v = *(const float4*)src;
    float sc = (r >= 32 && r < 64) ? LOG2E : 1.0f;   // pre-scale Q path
    ushort4 o;
    o.x = f2h(v.x * sc); o.y = f2h(v.y * sc);
    o.z = f2h(v.z * sc); o.w = f2h(v.w * sc);
    *(ushort4*)&Wall[e] = o;
    if (wb == 0 && t < 80) {
#pragma unroll
      for (int i = 0; i < 4; ++i) {
        int idx = t * 4 + i;
        ball[idx] = (idx < 32) ? bfp[idx]
                  : (idx < 64) ? bgp[idx - 32] * LOG2E
                               : bhp[idx - 64];
      }
    }
  }
}

// ---------------------------------------------------------------------------
// K1: projections via f16 MFMA (unchanged from R0).
// ---------------------------------------------------------------------------
__global__ __launch_bounds__(256, 4)
void k_proj(const u16* __restrict__ xT, const u16* __restrict__ Wall,
            const float* __restrict__ ball,
            u16* __restrict__ q, u16* __restrict__ kmat, u16* __restrict__ hbf)
{
  int bid = blockIdx.x, t = threadIdx.x;
  int w = t >> 6, l = t & 63, lg = l >> 4, li = l & 15;
  f32x4 Z = {0.f, 0.f, 0.f, 0.f};
  if (bid < 256) {        // ---- FG ----
    int b = bid >> 6, n0 = (bid & 63) << 6;
    int rbase = w * 16;
    half8 aw[8];
#pragma unroll
    for (int kk = 0; kk < 8; ++kk)
      aw[kk] = *(const half8*)&Wall[(rbase + li) * 256 + kk * 32 + lg * 8];
    float bias[4];
#pragma unroll
    for (int j = 0; j < 4; ++j) bias[j] = ball[rbase + 4 * lg + j];
#pragma unroll
    for (int nn = 0; nn < 4; ++nn) {
      int n = n0 + nn * 16 + li;
      f32x4 acc = Z;
#pragma unroll
      for (int kk = 0; kk < 8; ++kk) {
        half8 bx = *(const half8*)&xT[(size_t)(b * 4096 + n) * 256 + kk * 32 + lg * 8];
        acc = __builtin_amdgcn_mfma_f32_16x16x32_f16(aw[kk], bx, acc, 0, 0, 0);
      }
      ushort4 o;
      o.x = f2h(acc[0] + bias[0]); o.y = f2h(acc[1] + bias[1]);
      o.z = f2h(acc[2] + bias[2]); o.w = f2h(acc[3] + bias[3]);
      u16* dst = (rbase < 32)
               ? (kmat + (size_t)(b * 4096 + n) * 32 + rbase + 4 * lg)
               : (q    + (size_t)(b * 4096 + n) * 32 + (rbase - 32) + 4 * lg);
      *(ushort4*)dst = o;
    }
  } else {                // ---- H ----
    int hb = bid - 256;
    int b = hb >> 8, rt = (hb >> 6) & 3, n0 = (hb & 63) << 6;
    int r0 = 64 + rt * 64;
    int nbase = n0 + w * 16;
    half8 ax[8];
#pragma unroll
    for (int kk = 0; kk < 8; ++kk)
      ax[kk] = *(const half8*)&xT[(size_t)(b * 4096 + nbase + li) * 256 + kk * 32 + lg * 8];
#pragma unroll
    for (int rr = 0; rr < 4; ++rr) {
      int r = r0 + rr * 16 + li;
      f32x4 acc = Z;
#pragma unroll
      for (int kk = 0; kk < 8; ++kk) {
        half8 bw = *(const half8*)&Wall[r * 256 + kk * 32 + lg * 8];
        acc = __builtin_amdgcn_mfma_f32_16x16x32_f16(ax[kk], bw, acc, 0, 0, 0);
      }
      float bias = ball[r];
      ushort4 o;
      o.x = f2bf(acc[0] + bias); o.y = f2bf(acc[1] + bias);
      o.z = f2bf(acc[2] + bias); o.w = f2bf(acc[3] + bias);
      *(ushort4*)&hbf[(size_t)(b * 256 + r - 64) * 4096 + nbase + 4 * lg] = o;
    }
  }
}

// ---------------------------------------------------------------------------
// K2 v2: barrier-free in-register attention.
//  8 waves: msub(2) x ch(2) x kh(2). Each wave: 32 queries x 128 channels,
//  2048 keys. S_T = mfma32x32x16(K,Q) -> lane holds P[n][m=lane&31].
//  P packed to bf16 pairs (cvt_pk); fed to PV MFMA as A with a k-slot
//  permutation mirrored in the V loads (no cross-lane ops needed).
//  kh halves merged via LDS at the end; unnormalized row-sums -> divide once.
// ---------------------------------------------------------------------------
__global__ __launch_bounds__(512, 2)
void k_attn(const u16* __restrict__ q, const u16* __restrict__ kmat,
            const u16* __restrict__ hbf, const float* __restrict__ xin,
            const float* __restrict__ gam, float* __restrict__ out)
{
  __shared__ float accL[4 * 64 * 64];   // 64 KB kh-merge, XOR-swizzled
  __shared__ float vsL[64];
  __shared__ float invL[64];

  int bid = blockIdx.x, t = threadIdx.x;
  int xcd = bid & 7;
  int b = xcd >> 1;                         // batch pinned to 2 XCDs
  int mg = ((xcd & 1) << 5) | (bid >> 3);   // 0..63
  int m0 = mg << 6;
  int w = t >> 6, l = t & 63, l31 = l & 31, hi = l >> 5;
  int msub = w & 1, ch = (w >> 1) & 1, kh = w >> 2;
  int mb = m0 + msub * 32;
  int c0 = ch * 128;
  int nbase = kh * 2048;

  const u16* qb = q + (size_t)b * 4096 * 32;
  const u16* kb = kmat + (size_t)b * 4096 * 32;
  const u16* hb = hbf + (size_t)b * 256 * 4096;

  half8 qf0 = *(const half8*)&qb[(mb + l31) * 32 + hi * 8];
  half8 qf1 = *(const half8*)&qb[(mb + l31) * 32 + 16 + hi * 8];

  f32x16 Z16 = {0,0,0,0,0,0,0,0,0,0,0,0,0,0,0,0};
  f32x16 acc[4];
#pragma unroll
  for (int ct = 0; ct < 4; ++ct) acc[ct] = Z16;
  float vsum = 0.f;

  half8 kA0, kA1, kB0, kB1;
  uint4v vA[4][2], vB[4][2];

  auto loadK = [&](half8& k0, half8& k1, int n) {
    k0 = *(const half8*)&kb[(n + l31) * 32 + hi * 8];
    k1 = *(const half8*)&kb[(n + l31) * 32 + 16 + hi * 8];
  };
  auto loadV = [&](uint4v (&v)[4][2], int n) {
#pragma unroll
    for (int ct = 0; ct < 4; ++ct) {
      const u16* rb = hb + (size_t)(c0 + ct * 32 + l31) * 4096 + n + 4 * hi;
#pragma unroll
      for (int kc = 0; kc < 2; ++kc) {
        uint2 a = *(const uint2*)(rb + kc * 16);
        uint2 bq = *(const uint2*)(rb + kc * 16 + 8);
        uint4v vv = {a.x, a.y, bq.x, bq.y};   // n-slots {4hi+0..3, 8+4hi+0..3}
        v[ct][kc] = vv;
      }
    }
  };
  auto step = [&](half8 k0, half8 k1, uint4v (&v)[4][2]) {
    f32x16 sa = Z16;
    sa = __builtin_amdgcn_mfma_f32_32x32x16_f16(k0, qf0, sa, 0, 0, 0);
    sa = __builtin_amdgcn_mfma_f32_32x32x16_f16(k1, qf1, sa, 0, 0, 0);
    float p[16];
#pragma unroll
    for (int r = 0; r < 16; ++r) p[r] = exp2f(sa[r]);
    float s0 = 0.f, s1 = 0.f;
#pragma unroll
    for (int r = 0; r < 16; r += 2) { s0 += p[r]; s1 += p[r + 1]; }
    vsum += s0 + s1;
    u32 pk[8];
#pragma unroll
    for (int i = 0; i < 8; ++i) pk[i] = cvtpk_bf16(p[2 * i], p[2 * i + 1]);
    uint4v a0 = {pk[0], pk[1], pk[2], pk[3]};   // n 0..15 (slot-permuted)
    uint4v a1 = {pk[4], pk[5], pk[6], pk[7]};   // n 16..31
    short8 pa0 = __builtin_bit_cast(short8, a0);
    short8 pa1 = __builtin_bit_cast(short8, a1);
    __builtin_amdgcn_s_setprio(1);
#pragma unroll
    for (int ct = 0; ct < 4; ++ct) {
      acc[ct] = __builtin_amdgcn_mfma_f32_32x32x16_bf16(
          pa0, __builtin_bit_cast(short8, v[ct][0]), acc[ct], 0, 0, 0);
      acc[ct] = __builtin_amdgcn_mfma_f32_32x32x16_bf16(
          pa1, __builtin_bit_cast(short8, v[ct][1]), acc[ct], 0, 0, 0);
    }
    __builtin_amdgcn_s_setprio(0);
  };

  loadK(kA0, kA1, nbase);
  loadV(vA, nbase);

  for (int it = 0; it < 32; ++it) {
    int nB = nbase + it * 64 + 32;
    int nA2 = nbase + (((it + 1) * 64) & 2047);
    __builtin_amdgcn_s_barrier();          // raw rendezvous: keep L1 locality
    loadK(kB0, kB1, nB);
    loadV(vB, nB);
    step(kA0, kA1, vA);
    loadK(kA0, kA1, nA2);
    loadV(vA, nA2);
    step(kB0, kB1, vB);
  }

  // ---- epilogue: kh-merge + normalize + write ----
  float vt = vsum + __shfl_xor(vsum, 32);
  int region = w & 3;
  if (kh == 1) {
#pragma unroll
    for (int ct = 0; ct < 4; ++ct)
#pragma unroll
      for (int g = 0; g < 4; ++g) {
        int j4 = ct * 4 + g;
        float4 v4 = {acc[ct][4 * g], acc[ct][4 * g + 1],
                     acc[ct][4 * g + 2], acc[ct][4 * g + 3]};
        *(float4*)&accL[region * 4096 + l * 64 + ((j4 ^ (l & 15)) * 4)] = v4;
      }
    if (ch == 0 && l < 32) vsL[msub * 32 + l31] = vt;
  }
  __syncthreads();
  if (kh == 0) {
#pragma unroll
    for (int ct = 0; ct < 4; ++ct)
#pragma unroll
      for (int g = 0; g < 4; ++g) {
        int j4 = ct * 4 + g;
        float4 v4 = *(const float4*)&accL[region * 4096 + l * 64 + ((j4 ^ (l & 15)) * 4)];
        acc[ct][4 * g] += v4.x; acc[ct][4 * g + 1] += v4.y;
        acc[ct][4 * g + 2] += v4.z; acc[ct][4 * g + 3] += v4.w;
      }
    if (ch == 0 && l < 32)
      invL[msub * 32 + l31] = 1.0f / (vt + vsL[msub * 32 + l31]);
  }
  __syncthreads();
  if (kh == 0) {
    float gamma = gam[0];
    const float* xb = xin + (size_t)b * 256 * 4096;
    float* ob = out + (size_t)b * 256 * 4096;
#pragma unroll
    for (int g = 0; g < 4; ++g) {
      float4 inv4 = *(const float4*)&invL[msub * 32 + 8 * g + 4 * hi];
#pragma unroll
      for (int ct = 0; ct < 4; ++ct) {
        int c = c0 + ct * 32 + l31;
        size_t base = (size_t)c * 4096 + mb + 8 * g + 4 * hi;
        float4 xv = *(const float4*)&xb[base];
        float4 ov;
        ov.x = gamma * acc[ct][4 * g + 0] * inv4.x + xv.x;
        ov.y = gamma * acc[ct][4 * g + 1] * inv4.y + xv.y;
        ov.z = gamma * acc[ct][4 * g + 2] * inv4.z + xv.z;
        ov.w = gamma * acc[ct][4 * g + 3] * inv4.w + xv.w;
        *(float4*)&ob[base] = ov;
      }
    }
  }
}

// ---------------------------------------------------------------------------
extern "C" void kernel_launch(void* const* d_in, const int* in_sizes, int n_in,
                              void* d_out, int out_size, void* d_ws, size_t ws_size,
                              hipStream_t stream)
{
  const float* x   = (const float*)d_in[0];
  const float* Wf  = (const float*)d_in[1];
  const float* bfp = (const float*)d_in[2];
  const float* Wg  = (const float*)d_in[3];
  const float* bgp = (const float*)d_in[4];
  const float* Wh  = (const float*)d_in[5];
  const float* bhp = (const float*)d_in[6];
  const float* gam = (const float*)d_in[7];
  float* out = (float*)d_out;

  char* ws = (char*)d_ws;
  u16*   xT   = (u16*)(ws);                  // 8,388,608 B  f16 [4][4096][256]
  u16*   Wall = (u16*)(ws + 8388608);        //   163,840 B  f16 [320][256]
  float* ball = (float*)(ws + 8552448);      //     2,048 B  f32 [320]
  u16*   q    = (u16*)(ws + 8554496);        // 2,097,152 B  f16 [4][4096][32]  (g, *log2e)
  u16*   km   = (u16*)(ws + 10651648);       // 2,097,152 B  f16 [4][4096][32]  (f)
  u16*   hbf  = (u16*)(ws + 12748800);       // 8,388,608 B  bf16 [4][256][4096] (h)

  k_prep<<<dim3(1104), dim3(256), 0, stream>>>(x, Wf, bfp, Wg, bgp, Wh, bhp, xT, Wall, ball);
  k_proj<<<dim3(1280), dim3(256), 0, stream>>>(xT, Wall, ball, q, km, hbf);
  k_attn<<<dim3(256),  dim3(512), 0, stream>>>(q, km, hbf, x, gam, out);
}